// Round 4
// baseline (579.290 us; speedup 1.0000x reference)
//
#include <hip/hip_runtime.h>
#include <math.h>

// CapsNet dynamic routing, fully fused, 4 (b,n) pairs per block.
// Thread t owns output column o = t (k = t>>4, d = t&15); u_hat[k][i][d]
// lives in FOUR NAMED register arrays r0..r3 (never runtime-indexed; the
// R1/R2 r[g][i] form was demoted to scratch -> 1 GB scratch traffic).
// G=4 halves W-load instruction count and W L2 traffic vs G=2.
// b-update uses a split-halves tree: 30 shuffles reduce all 32 i-entries
// across the 16 d-lanes (vs 128 for the naive per-i butterfly).

#define IC 32
#define ID 16
#define NC 16
#define O  256            // NC*DC
#define CPAD 36           // cc/bb row stride: 36 floats = 144 B, 16B-aligned rows

__device__ __forceinline__ float reduce16(float v) {
    v += __shfl_xor(v, 1);
    v += __shfl_xor(v, 2);
    v += __shfl_xor(v, 4);
    v += __shfl_xor(v, 8);
    return v;
}

__device__ __forceinline__ float squash16(float v) {
    float s2 = reduce16(v * v);
    return v * (s2 / ((1.0f + s2) * sqrtf(s2 + 1e-7f)));
}

// b[k][i] (+)= sum_d out[k][d]*u_hat[k][i][d] for all 32 i, using the 16
// d-lanes cooperatively. After 4 split-exchange steps, lane d holds the
// fully d-reduced sums for i = base(d) and base(d)+1. ACC: 0 assign, 1 +=.
template <int ACC>
__device__ __forceinline__ void b_update(const float (&r)[IC], float out, int d,
                                         float* __restrict__ bbrow)
{
    float v[IC];
    #pragma unroll
    for (int j = 0; j < IC; ++j) v[j] = out * r[j];
    int base = 0;
    #pragma unroll
    for (int s = 0; s < 4; ++s) {
        const int mask = 1 << s;
        const int half = IC >> (s + 1);          // 16, 8, 4, 2
        const bool hi = (d & mask) != 0;
        if (hi) base += half;
        #pragma unroll
        for (int j = 0; j < half; ++j) {
            float send = hi ? v[j] : v[j + half];   // ship the half we discard
            float recv = __shfl_xor(send, mask);
            v[j] = (hi ? v[j + half] : v[j]) + recv;
        }
    }
    if (ACC) { bbrow[base] += v[0]; bbrow[base + 1] += v[1]; }
    else     { bbrow[base]  = v[0]; bbrow[base + 1]  = v[1]; }
}

__global__ __launch_bounds__(256, 2)
void capsule_routing_kernel(const float* __restrict__ inp,   // [B,N,IC,ID]
                            const float* __restrict__ W,     // [IC,ID,O]
                            float* __restrict__ outp)        // [B,N,NC,DC]
{
    const int t = threadIdx.x;
    const int pair0 = blockIdx.x * 4;

    __shared__ __align__(16) float bb[4][NC][CPAD];   // routing logits
    __shared__ __align__(16) float cc[4][NC][CPAD];   // softmax coeffs

    // ---- u_hat: rg[i] = sum_dd x_g[i][dd] * W[i][dd][t]
    float r0[IC], r1[IC], r2[IC], r3[IC];
    const float* x0 = inp + (size_t)pair0 * (IC * ID);
    const float* x1 = x0 + IC * ID;
    const float* x2 = x1 + IC * ID;
    const float* x3 = x2 + IC * ID;

    #pragma unroll
    for (int i = 0; i < IC; ++i) {
        float a0 = 0.f, a1 = 0.f, a2 = 0.f, a3 = 0.f;
        #pragma unroll
        for (int dd = 0; dd < ID; ++dd) {
            float w = W[(i * ID + dd) * O + t];   // coalesced, L2-resident
            a0 = fmaf(w, x0[i * ID + dd], a0);    // x block-uniform -> scalar loads
            a1 = fmaf(w, x1[i * ID + dd], a1);
            a2 = fmaf(w, x2[i * ID + dd], a2);
            a3 = fmaf(w, x3[i * ID + dd], a3);
        }
        r0[i] = a0; r1[i] = a1; r2[i] = a2; r3[i] = a3;
    }

    const int k = t >> 4;
    const int d = t & 15;
    float* bbr0 = &bb[0][k][0];
    float* bbr1 = &bb[1][k][0];
    float* bbr2 = &bb[2][k][0];
    float* bbr3 = &bb[3][k][0];

    // ---- routing iter 0: b = 0 -> c = 1/16 uniform (softmax skipped)
    float o0 = 0.f, o1 = 0.f, o2 = 0.f, o3 = 0.f;
    #pragma unroll
    for (int i = 0; i < IC; ++i) { o0 += r0[i]; o1 += r1[i]; o2 += r2[i]; o3 += r3[i]; }
    o0 = squash16(o0 * 0.0625f);
    o1 = squash16(o1 * 0.0625f);
    o2 = squash16(o2 * 0.0625f);
    o3 = squash16(o3 * 0.0625f);
    b_update<0>(r0, o0, d, bbr0);
    b_update<0>(r1, o1, d, bbr1);
    b_update<0>(r2, o2, d, bbr2);
    b_update<0>(r3, o3, d, bbr3);
    __syncthreads();

    #pragma unroll
    for (int it = 1; it < 3; ++it) {
        // ---- softmax over NC axis; 128 lanes: (pair p, input-capsule ii)
        if (t < 128) {
            const int p = t >> 5, ii = t & 31;
            float m = bb[p][0][ii];
            #pragma unroll
            for (int kk = 1; kk < NC; ++kk) m = fmaxf(m, bb[p][kk][ii]);
            float s = 0.f, e[NC];
            #pragma unroll
            for (int kk = 0; kk < NC; ++kk) { e[kk] = __expf(bb[p][kk][ii] - m); s += e[kk]; }
            float si = 1.0f / s;
            #pragma unroll
            for (int kk = 0; kk < NC; ++kk) cc[p][kk][ii] = e[kk] * si;
        }
        __syncthreads();

        // ---- out[k][d] = sum_i c[k][i]*u_hat[k][i][d], c read as float4
        const float4* c0 = (const float4*)&cc[0][k][0];
        const float4* c1 = (const float4*)&cc[1][k][0];
        const float4* c2 = (const float4*)&cc[2][k][0];
        const float4* c3 = (const float4*)&cc[3][k][0];
        o0 = 0.f; o1 = 0.f; o2 = 0.f; o3 = 0.f;
        #pragma unroll
        for (int q = 0; q < IC / 4; ++q) {
            float4 v0 = c0[q], v1 = c1[q], v2 = c2[q], v3 = c3[q];
            o0 = fmaf(v0.x, r0[4*q+0], o0); o0 = fmaf(v0.y, r0[4*q+1], o0);
            o0 = fmaf(v0.z, r0[4*q+2], o0); o0 = fmaf(v0.w, r0[4*q+3], o0);
            o1 = fmaf(v1.x, r1[4*q+0], o1); o1 = fmaf(v1.y, r1[4*q+1], o1);
            o1 = fmaf(v1.z, r1[4*q+2], o1); o1 = fmaf(v1.w, r1[4*q+3], o1);
            o2 = fmaf(v2.x, r2[4*q+0], o2); o2 = fmaf(v2.y, r2[4*q+1], o2);
            o2 = fmaf(v2.z, r2[4*q+2], o2); o2 = fmaf(v2.w, r2[4*q+3], o2);
            o3 = fmaf(v3.x, r3[4*q+0], o3); o3 = fmaf(v3.y, r3[4*q+1], o3);
            o3 = fmaf(v3.z, r3[4*q+2], o3); o3 = fmaf(v3.w, r3[4*q+3], o3);
        }

        if (it < 2) {
            o0 = squash16(o0); o1 = squash16(o1);
            o2 = squash16(o2); o3 = squash16(o3);
            b_update<1>(r0, o0, d, bbr0);
            b_update<1>(r1, o1, d, bbr1);
            b_update<1>(r2, o2, d, bbr2);
            b_update<1>(r3, o3, d, bbr3);
            __syncthreads();
        }
    }

    // ---- final iter: no squash; coalesced stores
    outp[(size_t)pair0 * O + t]       = o0;
    outp[((size_t)pair0 + 1) * O + t] = o1;
    outp[((size_t)pair0 + 2) * O + t] = o2;
    outp[((size_t)pair0 + 3) * O + t] = o3;
}

extern "C" void kernel_launch(void* const* d_in, const int* in_sizes, int n_in,
                              void* d_out, int out_size, void* d_ws, size_t ws_size,
                              hipStream_t stream) {
    const float* inp = (const float*)d_in[0];   // [32,128,32,16] fp32
    const float* W   = (const float*)d_in[1];   // [32,16,256]   fp32
    float* outp      = (float*)d_out;           // [32,128,16,16] fp32

    const int npairs = 32 * 128;                // B*N = 4096
    dim3 grid(npairs / 4), block(256);
    hipLaunchKernelGGL(capsule_routing_kernel, grid, block, 0, stream,
                       inp, W, outp);
}

// Round 5
// 134.344 us; speedup vs baseline: 4.3120x; 4.3120x over previous
//
#include <hip/hip_runtime.h>
#include <math.h>

// CapsNet dynamic routing, fully fused, 2 (b,n) pairs per block (G=2 is the
// verified no-spill point: R3 = 78 us @ VGPR 56; G=4 spilled twice).
// Thread t owns output column o = t (k = t>>4, d = t&15); u_hat[k][i][d]
// lives in TWO NAMED register arrays r0[i], r1[i] (never runtime-indexed).
// b-update: split-halves tree across the 16 d-lanes, with the out*r products
// formed on the fly in step 0 -> only a v[16] temp (R4's v[32] copy at G=4
// was the spill trigger). 34 shuffles per pair-iter vs 132 in R3.

#define IC 32
#define ID 16
#define NC 16
#define O  256            // NC*DC
#define CPAD 36           // bb/cc row stride: 144 B, 16B-aligned rows

__device__ __forceinline__ float reduce16(float v) {
    v += __shfl_xor(v, 1);
    v += __shfl_xor(v, 2);
    v += __shfl_xor(v, 4);
    v += __shfl_xor(v, 8);
    return v;
}

__device__ __forceinline__ float squash16(float v) {
    float s2 = reduce16(v * v);
    return v * (s2 / ((1.0f + s2) * sqrtf(s2 + 1e-7f)));
}

// b[k][i] (+)= sum_d out[k][d]*u_hat[k][i][d] for all 32 i, cooperatively
// across the 16 d-lanes. Step 0 exchanges halves of out*r[] formed on the
// fly (no v[32] copy); steps 1-3 run the tree on v[16]. Lane d ends owning
// the fully-reduced sums for i = base(d), base(d)+1. ACC: 0 assign, 1 +=.
template <int ACC>
__device__ __forceinline__ void b_update(const float (&r)[IC], float out, int d,
                                         float* __restrict__ bbrow)
{
    float v[16];
    const bool hi0 = (d & 1) != 0;
    #pragma unroll
    for (int j = 0; j < 16; ++j) {
        float send = out * (hi0 ? r[j] : r[j + 16]);   // ship the discarded half
        float keep = out * (hi0 ? r[j + 16] : r[j]);
        v[j] = keep + __shfl_xor(send, 1);
    }
    int base = hi0 ? 16 : 0;
    #pragma unroll
    for (int s = 1; s < 4; ++s) {
        const int mask = 1 << s;
        const int half = 16 >> s;                      // 8, 4, 2
        const bool hi = (d & mask) != 0;
        if (hi) base += half;
        #pragma unroll
        for (int j = 0; j < half; ++j) {
            float send = hi ? v[j] : v[j + half];
            float recv = __shfl_xor(send, mask);
            v[j] = (hi ? v[j + half] : v[j]) + recv;
        }
    }
    if (ACC) { bbrow[base] += v[0]; bbrow[base + 1] += v[1]; }
    else     { bbrow[base]  = v[0]; bbrow[base + 1]  = v[1]; }
}

__global__ __launch_bounds__(256, 4)
void capsule_routing_kernel(const float* __restrict__ inp,   // [B,N,IC,ID]
                            const float* __restrict__ W,     // [IC,ID,O]
                            float* __restrict__ outp)        // [B,N,NC,DC]
{
    const int t = threadIdx.x;
    const int pair0 = blockIdx.x * 2;

    __shared__ __align__(16) float bb[2][NC][CPAD];   // routing logits
    __shared__ __align__(16) float cc[2][NC][CPAD];   // softmax coeffs

    // ---- u_hat: rg[i] = sum_dd x_g[i][dd] * W[i][dd][t]
    float r0[IC], r1[IC];
    const float* x0 = inp + (size_t)pair0 * (IC * ID);
    const float* x1 = x0 + IC * ID;

    #pragma unroll
    for (int i = 0; i < IC; ++i) {
        float a0 = 0.f, a1 = 0.f;
        #pragma unroll
        for (int dd = 0; dd < ID; ++dd) {
            float w = W[(i * ID + dd) * O + t];   // coalesced, L2-resident
            a0 = fmaf(w, x0[i * ID + dd], a0);    // x block-uniform -> scalar loads
            a1 = fmaf(w, x1[i * ID + dd], a1);
        }
        r0[i] = a0; r1[i] = a1;
    }

    const int k = t >> 4;
    const int d = t & 15;
    float* bbr0 = &bb[0][k][0];
    float* bbr1 = &bb[1][k][0];

    // ---- routing iter 0: b = 0 -> c = 1/16 uniform (softmax skipped)
    float o0 = 0.f, o1 = 0.f;
    #pragma unroll
    for (int i = 0; i < IC; ++i) { o0 += r0[i]; o1 += r1[i]; }
    o0 = squash16(o0 * 0.0625f);
    o1 = squash16(o1 * 0.0625f);
    b_update<0>(r0, o0, d, bbr0);
    b_update<0>(r1, o1, d, bbr1);
    __syncthreads();

    #pragma unroll
    for (int it = 1; it < 3; ++it) {
        // ---- softmax over NC axis; lanes 0-31: pair0, 32-63: pair1
        if (t < 64) {
            const int p = t >> 5, ii = t & 31;
            float m = bb[p][0][ii];
            #pragma unroll
            for (int kk = 1; kk < NC; ++kk) m = fmaxf(m, bb[p][kk][ii]);
            float s = 0.f, e[NC];
            #pragma unroll
            for (int kk = 0; kk < NC; ++kk) { e[kk] = __expf(bb[p][kk][ii] - m); s += e[kk]; }
            float si = 1.0f / s;
            #pragma unroll
            for (int kk = 0; kk < NC; ++kk) cc[p][kk][ii] = e[kk] * si;
        }
        __syncthreads();

        // ---- out[k][d] = sum_i c[k][i]*u_hat[k][i][d], c read as float4
        const float4* c0 = (const float4*)&cc[0][k][0];
        const float4* c1 = (const float4*)&cc[1][k][0];
        o0 = 0.f; o1 = 0.f;
        #pragma unroll
        for (int q = 0; q < IC / 4; ++q) {
            float4 v0 = c0[q], v1 = c1[q];
            o0 = fmaf(v0.x, r0[4*q+0], o0); o0 = fmaf(v0.y, r0[4*q+1], o0);
            o0 = fmaf(v0.z, r0[4*q+2], o0); o0 = fmaf(v0.w, r0[4*q+3], o0);
            o1 = fmaf(v1.x, r1[4*q+0], o1); o1 = fmaf(v1.y, r1[4*q+1], o1);
            o1 = fmaf(v1.z, r1[4*q+2], o1); o1 = fmaf(v1.w, r1[4*q+3], o1);
        }

        if (it < 2) {
            o0 = squash16(o0);
            o1 = squash16(o1);
            b_update<1>(r0, o0, d, bbr0);
            b_update<1>(r1, o1, d, bbr1);
            __syncthreads();
        }
    }

    // ---- final iter: no squash; coalesced stores
    outp[(size_t)pair0 * O + t]       = o0;
    outp[((size_t)pair0 + 1) * O + t] = o1;
}

extern "C" void kernel_launch(void* const* d_in, const int* in_sizes, int n_in,
                              void* d_out, int out_size, void* d_ws, size_t ws_size,
                              hipStream_t stream) {
    const float* inp = (const float*)d_in[0];   // [32,128,32,16] fp32
    const float* W   = (const float*)d_in[1];   // [32,16,256]   fp32
    float* outp      = (float*)d_out;           // [32,128,16,16] fp32

    const int npairs = 32 * 128;                // B*N = 4096
    dim3 grid(npairs / 2), block(256);
    hipLaunchKernelGGL(capsule_routing_kernel, grid, block, 0, stream,
                       inp, W, outp);
}

// Round 7
// 79.436 us; speedup vs baseline: 7.2925x; 1.6912x over previous
//
#include <hip/hip_runtime.h>
#include <math.h>

// CapsNet dynamic routing, fully fused, 2 (b,n) pairs per block.
// Base = R3 (verified 78 us, zero scratch; compiler keeps r0/r1 in AGPRs).
// R6/R7 cuts DS-pipe ops ~3.5x (the dominant pipe: ~40 us of R3's 92):
//  - b_update: chunked split-halves tree, 8 i at a time (v[8] temp only;
//    R5's full-width v[16]+all-32-r-live version re-triggered scratch
//    demotion: 164 MB scratch writes).
//  - bb stored TRANSPOSED [pair][i][k] (pad 20): b_update scatter hits all
//    32 banks exactly once; softmax reads its 16 logits as 4x ds_read_b128.
//  - cc kept [pair][k][i] (pad 36): einsum reads float4, conflict-free
//    (rows staggered 4 banks, 16-lane broadcast within k-group).
// (R6 bench died to an unresponsive container — this is an unchanged
// resubmit to get a real measurement.)

#define IC 32
#define ID 16
#define NC 16
#define O  256            // NC*DC
#define BBPAD 20          // bb row stride (floats): 80 B, 16B-aligned rows
#define CPAD  36          // cc row stride (floats): 144 B, 16B-aligned rows

__device__ __forceinline__ float reduce16(float v) {
    v += __shfl_xor(v, 1);
    v += __shfl_xor(v, 2);
    v += __shfl_xor(v, 4);
    v += __shfl_xor(v, 8);
    return v;
}

__device__ __forceinline__ float squash16(float v) {
    float s2 = reduce16(v * v);
    return v * (s2 / ((1.0f + s2) * sqrtf(s2 + 1e-7f)));
}

// b[i][k] (+)= sum_d out[d]*u_hat[i][d], cooperatively across the 16
// d-lanes, 8 i-entries per chunk (keeps temp at v[8] and r accesses
// chunked -> register/AGPR friendly). Tree logic identical to R5 (passed
// correctness). bbcol = &bb[pair][0][k]; entry i lives at bbcol[i*BBPAD].
template <int ACC>
__device__ __forceinline__ void b_update(const float (&r)[IC], float out, int d,
                                         float* __restrict__ bbcol)
{
    #pragma unroll
    for (int c = 0; c < 4; ++c) {
        float v[8];
        #pragma unroll
        for (int j = 0; j < 8; ++j) v[j] = out * r[8 * c + j];
        int idx = 8 * c;
        #pragma unroll
        for (int s = 0; s < 3; ++s) {            // items 8 -> 4 -> 2 -> 1
            const int mask = 1 << s;
            const int half = 4 >> s;             // 4, 2, 1
            const bool hi = (d & mask) != 0;
            if (hi) idx += half;
            #pragma unroll
            for (int j = 0; j < half; ++j) {
                float recv = __shfl_xor(hi ? v[j] : v[j + half], mask);
                v[j] = (hi ? v[j + half] : v[j]) + recv;
            }
        }
        v[0] += __shfl_xor(v[0], 8);             // final 16-lane sum (dup on d, d+8)
        if (d < 8) {                             // 8 lanes x 4 chunks cover i=0..31
            if (ACC) bbcol[idx * BBPAD] += v[0];
            else     bbcol[idx * BBPAD]  = v[0];
        }
    }
}

__global__ __launch_bounds__(256, 4)
void capsule_routing_kernel(const float* __restrict__ inp,   // [B,N,IC,ID]
                            const float* __restrict__ W,     // [IC,ID,O]
                            float* __restrict__ outp)        // [B,N,NC,DC]
{
    const int t = threadIdx.x;
    const int pair0 = blockIdx.x * 2;

    __shared__ __align__(16) float bb[2][IC][BBPAD];  // logits, TRANSPOSED [i][k]
    __shared__ __align__(16) float cc[2][NC][CPAD];   // softmax coeffs [k][i]

    // ---- u_hat: rg[i] = sum_dd x_g[i][dd] * W[i][dd][t]
    float r0[IC], r1[IC];
    const float* x0 = inp + (size_t)pair0 * (IC * ID);
    const float* x1 = x0 + IC * ID;

    #pragma unroll
    for (int i = 0; i < IC; ++i) {
        float a0 = 0.f, a1 = 0.f;
        #pragma unroll
        for (int dd = 0; dd < ID; ++dd) {
            float w = W[(i * ID + dd) * O + t];   // coalesced, L2-resident
            a0 = fmaf(w, x0[i * ID + dd], a0);    // x block-uniform -> scalar loads
            a1 = fmaf(w, x1[i * ID + dd], a1);
        }
        r0[i] = a0; r1[i] = a1;
    }

    const int k = t >> 4;
    const int d = t & 15;
    float* bbc0 = &bb[0][0][k];
    float* bbc1 = &bb[1][0][k];

    // ---- routing iter 0: b = 0 -> c = 1/16 uniform (softmax skipped)
    float o0 = 0.f, o1 = 0.f;
    #pragma unroll
    for (int i = 0; i < IC; ++i) { o0 += r0[i]; o1 += r1[i]; }
    o0 = squash16(o0 * 0.0625f);
    o1 = squash16(o1 * 0.0625f);
    b_update<0>(r0, o0, d, bbc0);
    b_update<0>(r1, o1, d, bbc1);
    __syncthreads();

    #pragma unroll
    for (int it = 1; it < 3; ++it) {
        // ---- softmax over the NC axis; lanes 0-31: pair0, 32-63: pair1.
        // Thread ii reads its 16 logits contiguously (4x ds_read_b128).
        if (t < 64) {
            const int p = t >> 5, ii = t & 31;
            const float4* brow = (const float4*)&bb[p][ii][0];
            float4 b0 = brow[0], b1 = brow[1], b2 = brow[2], b3 = brow[3];
            float m = fmaxf(fmaxf(fmaxf(b0.x, b0.y), fmaxf(b0.z, b0.w)),
                            fmaxf(fmaxf(b1.x, b1.y), fmaxf(b1.z, b1.w)));
            m = fmaxf(m, fmaxf(fmaxf(fmaxf(b2.x, b2.y), fmaxf(b2.z, b2.w)),
                               fmaxf(fmaxf(b3.x, b3.y), fmaxf(b3.z, b3.w))));
            b0.x = __expf(b0.x - m); b0.y = __expf(b0.y - m);
            b0.z = __expf(b0.z - m); b0.w = __expf(b0.w - m);
            b1.x = __expf(b1.x - m); b1.y = __expf(b1.y - m);
            b1.z = __expf(b1.z - m); b1.w = __expf(b1.w - m);
            b2.x = __expf(b2.x - m); b2.y = __expf(b2.y - m);
            b2.z = __expf(b2.z - m); b2.w = __expf(b2.w - m);
            b3.x = __expf(b3.x - m); b3.y = __expf(b3.y - m);
            b3.z = __expf(b3.z - m); b3.w = __expf(b3.w - m);
            float s = ((b0.x + b0.y) + (b0.z + b0.w))
                    + ((b1.x + b1.y) + (b1.z + b1.w))
                    + ((b2.x + b2.y) + (b2.z + b2.w))
                    + ((b3.x + b3.y) + (b3.z + b3.w));
            float si = 1.0f / s;
            cc[p][ 0][ii] = b0.x * si; cc[p][ 1][ii] = b0.y * si;
            cc[p][ 2][ii] = b0.z * si; cc[p][ 3][ii] = b0.w * si;
            cc[p][ 4][ii] = b1.x * si; cc[p][ 5][ii] = b1.y * si;
            cc[p][ 6][ii] = b1.z * si; cc[p][ 7][ii] = b1.w * si;
            cc[p][ 8][ii] = b2.x * si; cc[p][ 9][ii] = b2.y * si;
            cc[p][10][ii] = b2.z * si; cc[p][11][ii] = b2.w * si;
            cc[p][12][ii] = b3.x * si; cc[p][13][ii] = b3.y * si;
            cc[p][14][ii] = b3.z * si; cc[p][15][ii] = b3.w * si;
        }
        __syncthreads();

        // ---- out[k][d] = sum_i c[k][i]*u_hat[k][i][d], c read as float4
        const float4* c0 = (const float4*)&cc[0][k][0];
        const float4* c1 = (const float4*)&cc[1][k][0];
        o0 = 0.f; o1 = 0.f;
        #pragma unroll
        for (int q = 0; q < IC / 4; ++q) {
            float4 v0 = c0[q], v1 = c1[q];
            o0 = fmaf(v0.x, r0[4*q+0], o0); o0 = fmaf(v0.y, r0[4*q+1], o0);
            o0 = fmaf(v0.z, r0[4*q+2], o0); o0 = fmaf(v0.w, r0[4*q+3], o0);
            o1 = fmaf(v1.x, r1[4*q+0], o1); o1 = fmaf(v1.y, r1[4*q+1], o1);
            o1 = fmaf(v1.z, r1[4*q+2], o1); o1 = fmaf(v1.w, r1[4*q+3], o1);
        }

        if (it < 2) {
            o0 = squash16(o0);
            o1 = squash16(o1);
            b_update<1>(r0, o0, d, bbc0);
            b_update<1>(r1, o1, d, bbc1);
            __syncthreads();
        }
    }

    // ---- final iter: no squash; coalesced stores
    outp[(size_t)pair0 * O + t]       = o0;
    outp[((size_t)pair0 + 1) * O + t] = o1;
}

extern "C" void kernel_launch(void* const* d_in, const int* in_sizes, int n_in,
                              void* d_out, int out_size, void* d_ws, size_t ws_size,
                              hipStream_t stream) {
    const float* inp = (const float*)d_in[0];   // [32,128,32,16] fp32
    const float* W   = (const float*)d_in[1];   // [32,16,256]   fp32
    float* outp      = (float*)d_out;           // [32,128,16,16] fp32

    const int npairs = 32 * 128;                // B*N = 4096
    dim3 grid(npairs / 2), block(256);
    hipLaunchKernelGGL(capsule_routing_kernel, grid, block, 0, stream,
                       inp, W, outp);
}